// Round 2
// baseline (1881.538 us; speedup 1.0000x reference)
//
#include <hip/hip_runtime.h>

#define NN 50000
#define NE 1000000
#define KF 256      // IN_FEAT
#define HD 128      // HIDDEN

// ---------------- workspace layout ----------------
// g    : NN*HD floats  (h * dinv[row])
// dinv : NN floats     (deg, then rsqrt(deg) in place)

__global__ __launch_bounds__(256) void k_deg_init(float* __restrict__ deg) {
    int i = blockIdx.x * blockDim.x + threadIdx.x;
    if (i < NN) deg[i] = 1.0f;  // self-loop
}

__global__ __launch_bounds__(256) void k_deg_count(const int* __restrict__ cols,
                                                   float* __restrict__ deg) {
    int e = blockIdx.x * blockDim.x + threadIdx.x;
    if (e < NE) atomicAdd(&deg[cols[e]], 1.0f);
}

__global__ __launch_bounds__(256) void k_dinv(float* __restrict__ deg) {
    int i = blockIdx.x * blockDim.x + threadIdx.x;
    if (i < NN) deg[i] = rsqrtf(deg[i]);  // deg >= 1 always (self-loop)
}

// GEMM: g[r][c] = dinv[r] * sum_k x[r][k] * W[k][c]
// Block computes 64 rows x 128 cols; 256 threads; thread tile 8x4.
#define BM 64
#define BK 32

__global__ __launch_bounds__(256) void k_gemm(const float* __restrict__ x,
                                              const float* __restrict__ W,
                                              const float* __restrict__ dinv,
                                              float* __restrict__ g) {
    __shared__ __align__(16) float sx[BK][BM + 1];  // x tile, transposed
    __shared__ __align__(16) float sw[BK][HD];      // W tile

    const int tid = threadIdx.x;
    const int bm0 = blockIdx.x * BM;
    const int tx = tid & 31;   // col quad 0..31 -> cols tx*4..tx*4+3
    const int ty = tid >> 5;   // row group 0..7 -> rows ty*8..ty*8+7

    float acc[8][4] = {};

    for (int k0 = 0; k0 < KF; k0 += BK) {
        // stage x tile: 64 rows x 32 k = 512 float4, 2 per thread
        #pragma unroll
        for (int l = 0; l < 2; ++l) {
            int idx = tid + l * 256;
            int r  = idx >> 3;   // 0..63
            int kq = idx & 7;    // k quad 0..7
            int grow = bm0 + r;
            float4 v = make_float4(0.f, 0.f, 0.f, 0.f);
            if (grow < NN)
                v = *(const float4*)(&x[(size_t)grow * KF + k0 + kq * 4]);
            sx[kq * 4 + 0][r] = v.x;
            sx[kq * 4 + 1][r] = v.y;
            sx[kq * 4 + 2][r] = v.z;
            sx[kq * 4 + 3][r] = v.w;
        }
        // stage W tile: 32 k x 128 cols = 1024 float4, 4 per thread
        #pragma unroll
        for (int l = 0; l < 4; ++l) {
            int idx = tid + l * 256;
            int kr = idx >> 5;   // 0..31
            int cq = idx & 31;   // 0..31
            *(float4*)(&sw[kr][cq * 4]) =
                *(const float4*)(&W[(size_t)(k0 + kr) * HD + cq * 4]);
        }
        __syncthreads();

        #pragma unroll
        for (int kk = 0; kk < BK; ++kk) {
            float xv[8];
            #pragma unroll
            for (int i = 0; i < 8; ++i) xv[i] = sx[kk][ty * 8 + i];
            float4 wv = *(const float4*)(&sw[kk][tx * 4]);
            #pragma unroll
            for (int i = 0; i < 8; ++i) {
                acc[i][0] += xv[i] * wv.x;
                acc[i][1] += xv[i] * wv.y;
                acc[i][2] += xv[i] * wv.z;
                acc[i][3] += xv[i] * wv.w;
            }
        }
        __syncthreads();
    }

    #pragma unroll
    for (int i = 0; i < 8; ++i) {
        int grow = bm0 + ty * 8 + i;
        if (grow < NN) {
            float s = dinv[grow];
            float4 o = make_float4(acc[i][0] * s, acc[i][1] * s,
                                   acc[i][2] * s, acc[i][3] * s);
            *(float4*)(&g[(size_t)grow * HD + tx * 4]) = o;
        }
    }
}

// out[i][:] = b[:] + g[i][:] * dinv[i]   (bias + self-loop message)
__global__ __launch_bounds__(256) void k_out_init(const float* __restrict__ g,
                                                  const float* __restrict__ dinv,
                                                  const float* __restrict__ b,
                                                  float* __restrict__ out) {
    int idx = blockIdx.x * blockDim.x + threadIdx.x;  // float4 index
    const int total = NN * HD / 4;
    if (idx >= total) return;
    int node = idx >> 5;  // 32 float4 per node
    int q    = idx & 31;
    float s = dinv[node];
    float4 gv = *(const float4*)(&g[(size_t)idx * 4]);
    float4 bv = *(const float4*)(&b[q * 4]);
    float4 o = make_float4(bv.x + gv.x * s, bv.y + gv.y * s,
                           bv.z + gv.z * s, bv.w + gv.w * s);
    *(float4*)(&out[(size_t)idx * 4]) = o;
}

// per-edge scatter: 32 lanes per edge, float4 gather + 4 atomics/lane
__global__ __launch_bounds__(256) void k_scatter(const int* __restrict__ rows,
                                                 const int* __restrict__ cols,
                                                 const float* __restrict__ g,
                                                 const float* __restrict__ dinv,
                                                 float* __restrict__ out) {
    int t = blockIdx.x * blockDim.x + threadIdx.x;
    int e    = t >> 5;
    int lane = t & 31;
    if (e >= NE) return;
    int r = rows[e];
    int c = cols[e];
    float s = dinv[c];
    float4 gv = *(const float4*)(&g[(size_t)r * HD + lane * 4]);
    float* o = &out[(size_t)c * HD + lane * 4];
    atomicAdd(o + 0, gv.x * s);
    atomicAdd(o + 1, gv.y * s);
    atomicAdd(o + 2, gv.z * s);
    atomicAdd(o + 3, gv.w * s);
}

extern "C" void kernel_launch(void* const* d_in, const int* in_sizes, int n_in,
                              void* d_out, int out_size, void* d_ws, size_t ws_size,
                              hipStream_t stream) {
    const float* x  = (const float*)d_in[0];
    const int*   ei = (const int*)d_in[1];   // [2][NE]: rows then cols
    const float* W  = (const float*)d_in[2];
    const float* b  = (const float*)d_in[3];
    float* out = (float*)d_out;

    float* g    = (float*)d_ws;              // NN*HD
    float* dinv = g + (size_t)NN * HD;       // NN

    const int* rows = ei;
    const int* cols = ei + NE;

    k_deg_init<<<(NN + 255) / 256, 256, 0, stream>>>(dinv);
    k_deg_count<<<(NE + 255) / 256, 256, 0, stream>>>(cols, dinv);
    k_dinv<<<(NN + 255) / 256, 256, 0, stream>>>(dinv);
    k_gemm<<<(NN + BM - 1) / BM, 256, 0, stream>>>(x, W, dinv, g);
    k_out_init<<<(NN * HD / 4 + 255) / 256, 256, 0, stream>>>(g, dinv, b, out);
    k_scatter<<<(int)(((size_t)NE * 32 + 255) / 256), 256, 0, stream>>>(rows, cols, g, dinv, out);
}

// Round 6
// 449.639 us; speedup vs baseline: 4.1845x; 4.1845x over previous
//
#include <hip/hip_runtime.h>

#define NN 50000
#define NE 1000000
#define KF 256      // IN_FEAT
#define HD 128      // HIDDEN

// ---------------- workspace layout (see kernel_launch) ----------------
// g       : NN*HD floats   (h * dinv[row])
// dinv    : NN floats
// counts  : NN ints        (histogram, then reused as fill cursor)
// offsets : NN+1 ints      (CSR row pointers by destination)
// srcs    : NE ints        (edge sources, bucketed by destination)

__global__ __launch_bounds__(256) void k_zero(int* __restrict__ counts) {
    int i = blockIdx.x * blockDim.x + threadIdx.x;
    if (i < NN) counts[i] = 0;
}

__global__ __launch_bounds__(256) void k_count(const int* __restrict__ cols,
                                               int* __restrict__ counts) {
    int e = blockIdx.x * blockDim.x + threadIdx.x;
    if (e < NE) atomicAdd(&counts[cols[e]], 1);
}

// Single-block exclusive scan of counts -> offsets; also dinv = rsqrt(deg+1)
// and reset counts to 0 (reused as fill cursors).
#define SCAN_T 1024
__global__ __launch_bounds__(SCAN_T) void k_scan(int* __restrict__ counts,
                                                 int* __restrict__ offsets,
                                                 float* __restrict__ dinv) {
    __shared__ int part[SCAN_T];
    const int t = threadIdx.x;
    const int CHUNK = (NN + SCAN_T - 1) / SCAN_T;  // 49
    const int begin = t * CHUNK;
    const int end   = begin + CHUNK < NN ? begin + CHUNK : NN;

    int s = 0;
    for (int i = begin; i < end; ++i) s += counts[i];
    part[t] = s;
    __syncthreads();
    // Hillis-Steele inclusive scan over 1024 partials
    for (int off = 1; off < SCAN_T; off <<= 1) {
        int v = (t >= off) ? part[t - off] : 0;
        __syncthreads();
        part[t] += v;
        __syncthreads();
    }
    int run = (t > 0) ? part[t - 1] : 0;  // exclusive prefix of this chunk
    for (int i = begin; i < end; ++i) {
        int c = counts[i];
        offsets[i] = run;
        dinv[i] = rsqrtf((float)(c + 1));   // +1 self-loop
        counts[i] = 0;                       // reset cursor
        run += c;
    }
    if (t == SCAN_T - 1) offsets[NN] = run;  // == NE
}

__global__ __launch_bounds__(256) void k_fill(const int* __restrict__ rows,
                                              const int* __restrict__ cols,
                                              const int* __restrict__ offsets,
                                              int* __restrict__ cursor,
                                              int* __restrict__ srcs) {
    int e = blockIdx.x * blockDim.x + threadIdx.x;
    if (e >= NE) return;
    int c = cols[e];
    int slot = atomicAdd(&cursor[c], 1);
    srcs[offsets[c] + slot] = rows[e];
}

// GEMM: g[r][c] = dinv[r] * sum_k x[r][k] * W[k][c]
// Block computes 64 rows x 128 cols; 256 threads; thread tile 8x4.
#define BM 64
#define BK 32

__global__ __launch_bounds__(256) void k_gemm(const float* __restrict__ x,
                                              const float* __restrict__ W,
                                              const float* __restrict__ dinv,
                                              float* __restrict__ g) {
    __shared__ __align__(16) float sx[BK][BM + 1];  // x tile, transposed
    __shared__ __align__(16) float sw[BK][HD];      // W tile

    const int tid = threadIdx.x;
    const int bm0 = blockIdx.x * BM;
    const int tx = tid & 31;   // col quad 0..31 -> cols tx*4..tx*4+3
    const int ty = tid >> 5;   // row group 0..7 -> rows ty*8..ty*8+7

    float acc[8][4] = {};

    for (int k0 = 0; k0 < KF; k0 += BK) {
        #pragma unroll
        for (int l = 0; l < 2; ++l) {
            int idx = tid + l * 256;
            int r  = idx >> 3;
            int kq = idx & 7;
            int grow = bm0 + r;
            float4 v = make_float4(0.f, 0.f, 0.f, 0.f);
            if (grow < NN)
                v = *(const float4*)(&x[(size_t)grow * KF + k0 + kq * 4]);
            sx[kq * 4 + 0][r] = v.x;
            sx[kq * 4 + 1][r] = v.y;
            sx[kq * 4 + 2][r] = v.z;
            sx[kq * 4 + 3][r] = v.w;
        }
        #pragma unroll
        for (int l = 0; l < 4; ++l) {
            int idx = tid + l * 256;
            int kr = idx >> 5;
            int cq = idx & 31;
            *(float4*)(&sw[kr][cq * 4]) =
                *(const float4*)(&W[(size_t)(k0 + kr) * HD + cq * 4]);
        }
        __syncthreads();

        #pragma unroll
        for (int kk = 0; kk < BK; ++kk) {
            float xv[8];
            #pragma unroll
            for (int i = 0; i < 8; ++i) xv[i] = sx[kk][ty * 8 + i];
            float4 wv = *(const float4*)(&sw[kk][tx * 4]);
            #pragma unroll
            for (int i = 0; i < 8; ++i) {
                acc[i][0] += xv[i] * wv.x;
                acc[i][1] += xv[i] * wv.y;
                acc[i][2] += xv[i] * wv.z;
                acc[i][3] += xv[i] * wv.w;
            }
        }
        __syncthreads();
    }

    #pragma unroll
    for (int i = 0; i < 8; ++i) {
        int grow = bm0 + ty * 8 + i;
        if (grow < NN) {
            float s = dinv[grow];
            float4 o = make_float4(acc[i][0] * s, acc[i][1] * s,
                                   acc[i][2] * s, acc[i][3] * s);
            *(float4*)(&g[(size_t)grow * HD + tx * 4]) = o;
        }
    }
}

// Gather-reduce: 32 lanes per node; out[c] = b + dinv[c]*(g[c] + sum_in g[src])
__global__ __launch_bounds__(256) void k_aggregate(const int* __restrict__ offsets,
                                                   const int* __restrict__ srcs,
                                                   const float* __restrict__ g,
                                                   const float* __restrict__ dinv,
                                                   const float* __restrict__ b,
                                                   float* __restrict__ out) {
    int t = blockIdx.x * blockDim.x + threadIdx.x;
    int c    = t >> 5;
    int lane = t & 31;
    if (c >= NN) return;
    const int s0 = offsets[c];
    const int s1 = offsets[c + 1];

    // self-loop message: g[c] (norm dinv[c]*dinv[c], one factor folded below)
    float4 acc = *(const float4*)(&g[(size_t)c * HD + lane * 4]);

    int s = s0;
    for (; s + 1 < s1; s += 2) {  // 2-way unroll for load-latency overlap
        int r0 = srcs[s];
        int r1 = srcs[s + 1];
        float4 a0 = *(const float4*)(&g[(size_t)r0 * HD + lane * 4]);
        float4 a1 = *(const float4*)(&g[(size_t)r1 * HD + lane * 4]);
        acc.x += a0.x; acc.y += a0.y; acc.z += a0.z; acc.w += a0.w;
        acc.x += a1.x; acc.y += a1.y; acc.z += a1.z; acc.w += a1.w;
    }
    if (s < s1) {
        int r0 = srcs[s];
        float4 a0 = *(const float4*)(&g[(size_t)r0 * HD + lane * 4]);
        acc.x += a0.x; acc.y += a0.y; acc.z += a0.z; acc.w += a0.w;
    }

    float sc = dinv[c];
    float4 bv = *(const float4*)(&b[lane * 4]);
    float4 o = make_float4(bv.x + sc * acc.x, bv.y + sc * acc.y,
                           bv.z + sc * acc.z, bv.w + sc * acc.w);
    *(float4*)(&out[(size_t)c * HD + lane * 4]) = o;
}

extern "C" void kernel_launch(void* const* d_in, const int* in_sizes, int n_in,
                              void* d_out, int out_size, void* d_ws, size_t ws_size,
                              hipStream_t stream) {
    const float* x  = (const float*)d_in[0];
    const int*   ei = (const int*)d_in[1];   // [2][NE]: rows then cols
    const float* W  = (const float*)d_in[2];
    const float* b  = (const float*)d_in[3];
    float* out = (float*)d_out;

    float* g       = (float*)d_ws;                       // NN*HD
    float* dinv    = g + (size_t)NN * HD;                // NN
    int*   counts  = (int*)(dinv + NN);                  // NN
    int*   offsets = counts + NN;                        // NN+1
    int*   srcs    = offsets + NN + 1;                   // NE

    const int* rows = ei;
    const int* cols = ei + NE;

    k_zero <<<(NN + 255) / 256, 256, 0, stream>>>(counts);
    k_count<<<(NE + 255) / 256, 256, 0, stream>>>(cols, counts);
    k_scan <<<1, SCAN_T, 0, stream>>>(counts, offsets, dinv);
    k_fill <<<(NE + 255) / 256, 256, 0, stream>>>(rows, cols, offsets, counts, srcs);
    k_gemm <<<(NN + BM - 1) / BM, 256, 0, stream>>>(x, W, dinv, g);
    k_aggregate<<<(int)(((size_t)NN * 32 + 255) / 256), 256, 0, stream>>>(
        offsets, srcs, g, dinv, b, out);
}

// Round 7
// 322.408 us; speedup vs baseline: 5.8359x; 1.3946x over previous
//
#include <hip/hip_runtime.h>

#define NN 50000
#define NE 1000000
#define KF 256      // IN_FEAT
#define HD 128      // HIDDEN
#define NBLK ((NN + 255) / 256)   // 196 scan blocks

// ---------------- workspace layout (see kernel_launch) ----------------
// g       : NN*HD floats   (h * dinv[row])
// dinv    : NN floats
// counts  : NN ints        (histogram, then reused as fill cursor)
// offsets : NN+1 ints      (CSR row pointers by destination)
// srcs    : NE ints        (edge sources, bucketed by destination)
// bsum    : NBLK ints      (block sums for two-level scan)

__global__ __launch_bounds__(256) void k_zero(int* __restrict__ counts) {
    int i = blockIdx.x * blockDim.x + threadIdx.x;
    if (i < NN) counts[i] = 0;
}

__global__ __launch_bounds__(256) void k_count(const int* __restrict__ cols,
                                               int* __restrict__ counts) {
    int e = blockIdx.x * blockDim.x + threadIdx.x;
    if (e < NE) atomicAdd(&counts[cols[e]], 1);
}

// ---- two-level scan: blocksum -> scan block sums -> per-block offsets ----
__global__ __launch_bounds__(256) void k_blocksum(const int* __restrict__ counts,
                                                  int* __restrict__ bsum) {
    __shared__ int red[256];
    int t = threadIdx.x;
    int i = blockIdx.x * 256 + t;
    red[t] = (i < NN) ? counts[i] : 0;
    __syncthreads();
    #pragma unroll
    for (int off = 128; off > 0; off >>= 1) {
        if (t < off) red[t] += red[t + off];
        __syncthreads();
    }
    if (t == 0) bsum[blockIdx.x] = red[0];
}

__global__ __launch_bounds__(256) void k_scanb(int* __restrict__ bsum) {
    __shared__ int part[256];
    int t = threadIdx.x;
    part[t] = (t < NBLK) ? bsum[t] : 0;
    __syncthreads();
    #pragma unroll
    for (int off = 1; off < 256; off <<= 1) {
        int v = (t >= off) ? part[t - off] : 0;
        __syncthreads();
        part[t] += v;
        __syncthreads();
    }
    if (t < NBLK) bsum[t] = (t > 0) ? part[t - 1] : 0;  // exclusive
}

__global__ __launch_bounds__(256) void k_offsets(int* __restrict__ counts,
                                                 const int* __restrict__ bsum,
                                                 int* __restrict__ offsets,
                                                 float* __restrict__ dinv) {
    __shared__ int part[256];
    int t = threadIdx.x;
    int i = blockIdx.x * 256 + t;
    int c = (i < NN) ? counts[i] : 0;
    part[t] = c;
    __syncthreads();
    #pragma unroll
    for (int off = 1; off < 256; off <<= 1) {
        int v = (t >= off) ? part[t - off] : 0;
        __syncthreads();
        part[t] += v;
        __syncthreads();
    }
    if (i < NN) {
        int excl = part[t] - c;  // inclusive - self
        offsets[i] = bsum[blockIdx.x] + excl;
        dinv[i] = rsqrtf((float)(c + 1));   // +1 self-loop
        counts[i] = 0;                       // reset cursor for k_fill
    }
    if (i == 0) offsets[NN] = NE;            // total is the known constant
}

__global__ __launch_bounds__(256) void k_fill(const int* __restrict__ rows,
                                              const int* __restrict__ cols,
                                              const int* __restrict__ offsets,
                                              int* __restrict__ cursor,
                                              int* __restrict__ srcs) {
    int e = blockIdx.x * blockDim.x + threadIdx.x;
    if (e >= NE) return;
    int c = cols[e];
    int slot = atomicAdd(&cursor[c], 1);
    srcs[offsets[c] + slot] = rows[e];
}

// GEMM: g[r][c] = dinv[r] * sum_k x[r][k] * W[k][c]
// Block computes 64 rows x 128 cols; 256 threads; thread tile 8x4.
#define BM 64
#define BK 32

__global__ __launch_bounds__(256) void k_gemm(const float* __restrict__ x,
                                              const float* __restrict__ W,
                                              const float* __restrict__ dinv,
                                              float* __restrict__ g) {
    __shared__ __align__(16) float sx[BK][BM + 1];  // x tile, transposed
    __shared__ __align__(16) float sw[BK][HD];      // W tile

    const int tid = threadIdx.x;
    const int bm0 = blockIdx.x * BM;
    const int tx = tid & 31;   // col quad 0..31 -> cols tx*4..tx*4+3
    const int ty = tid >> 5;   // row group 0..7 -> rows ty*8..ty*8+7

    float acc[8][4] = {};

    for (int k0 = 0; k0 < KF; k0 += BK) {
        #pragma unroll
        for (int l = 0; l < 2; ++l) {
            int idx = tid + l * 256;
            int r  = idx >> 3;
            int kq = idx & 7;
            int grow = bm0 + r;
            float4 v = make_float4(0.f, 0.f, 0.f, 0.f);
            if (grow < NN)
                v = *(const float4*)(&x[(size_t)grow * KF + k0 + kq * 4]);
            sx[kq * 4 + 0][r] = v.x;
            sx[kq * 4 + 1][r] = v.y;
            sx[kq * 4 + 2][r] = v.z;
            sx[kq * 4 + 3][r] = v.w;
        }
        #pragma unroll
        for (int l = 0; l < 4; ++l) {
            int idx = tid + l * 256;
            int kr = idx >> 5;
            int cq = idx & 31;
            *(float4*)(&sw[kr][cq * 4]) =
                *(const float4*)(&W[(size_t)(k0 + kr) * HD + cq * 4]);
        }
        __syncthreads();

        #pragma unroll
        for (int kk = 0; kk < BK; ++kk) {
            float xv[8];
            #pragma unroll
            for (int i = 0; i < 8; ++i) xv[i] = sx[kk][ty * 8 + i];
            float4 wv = *(const float4*)(&sw[kk][tx * 4]);
            #pragma unroll
            for (int i = 0; i < 8; ++i) {
                acc[i][0] += xv[i] * wv.x;
                acc[i][1] += xv[i] * wv.y;
                acc[i][2] += xv[i] * wv.z;
                acc[i][3] += xv[i] * wv.w;
            }
        }
        __syncthreads();
    }

    #pragma unroll
    for (int i = 0; i < 8; ++i) {
        int grow = bm0 + ty * 8 + i;
        if (grow < NN) {
            float s = dinv[grow];
            float4 o = make_float4(acc[i][0] * s, acc[i][1] * s,
                                   acc[i][2] * s, acc[i][3] * s);
            *(float4*)(&g[(size_t)grow * HD + tx * 4]) = o;
        }
    }
}

// Gather-reduce: 32 lanes per node; out[c] = b + dinv[c]*(g[c] + sum_in g[src])
__global__ __launch_bounds__(256) void k_aggregate(const int* __restrict__ offsets,
                                                   const int* __restrict__ srcs,
                                                   const float* __restrict__ g,
                                                   const float* __restrict__ dinv,
                                                   const float* __restrict__ b,
                                                   float* __restrict__ out) {
    int t = blockIdx.x * blockDim.x + threadIdx.x;
    int c    = t >> 5;
    int lane = t & 31;
    if (c >= NN) return;
    const int s0 = offsets[c];
    const int s1 = offsets[c + 1];

    // self-loop message: g[c] (norm dinv[c]*dinv[c], one factor folded below)
    float4 acc = *(const float4*)(&g[(size_t)c * HD + lane * 4]);

    int s = s0;
    for (; s + 1 < s1; s += 2) {  // 2-way unroll for load-latency overlap
        int r0 = srcs[s];
        int r1 = srcs[s + 1];
        float4 a0 = *(const float4*)(&g[(size_t)r0 * HD + lane * 4]);
        float4 a1 = *(const float4*)(&g[(size_t)r1 * HD + lane * 4]);
        acc.x += a0.x; acc.y += a0.y; acc.z += a0.z; acc.w += a0.w;
        acc.x += a1.x; acc.y += a1.y; acc.z += a1.z; acc.w += a1.w;
    }
    if (s < s1) {
        int r0 = srcs[s];
        float4 a0 = *(const float4*)(&g[(size_t)r0 * HD + lane * 4]);
        acc.x += a0.x; acc.y += a0.y; acc.z += a0.z; acc.w += a0.w;
    }

    float sc = dinv[c];
    float4 bv = *(const float4*)(&b[lane * 4]);
    float4 o = make_float4(bv.x + sc * acc.x, bv.y + sc * acc.y,
                           bv.z + sc * acc.z, bv.w + sc * acc.w);
    *(float4*)(&out[(size_t)c * HD + lane * 4]) = o;
}

extern "C" void kernel_launch(void* const* d_in, const int* in_sizes, int n_in,
                              void* d_out, int out_size, void* d_ws, size_t ws_size,
                              hipStream_t stream) {
    const float* x  = (const float*)d_in[0];
    const int*   ei = (const int*)d_in[1];   // [2][NE]: rows then cols
    const float* W  = (const float*)d_in[2];
    const float* b  = (const float*)d_in[3];
    float* out = (float*)d_out;

    float* g       = (float*)d_ws;                       // NN*HD
    float* dinv    = g + (size_t)NN * HD;                // NN
    int*   counts  = (int*)(dinv + NN);                  // NN
    int*   offsets = counts + NN;                        // NN+1
    int*   srcs    = offsets + NN + 1;                   // NE
    int*   bsum    = srcs + NE;                          // NBLK

    const int* rows = ei;
    const int* cols = ei + NE;

    k_zero    <<<(NN + 255) / 256, 256, 0, stream>>>(counts);
    k_count   <<<(NE + 255) / 256, 256, 0, stream>>>(cols, counts);
    k_blocksum<<<NBLK, 256, 0, stream>>>(counts, bsum);
    k_scanb   <<<1, 256, 0, stream>>>(bsum);
    k_offsets <<<NBLK, 256, 0, stream>>>(counts, bsum, offsets, dinv);
    k_fill    <<<(NE + 255) / 256, 256, 0, stream>>>(rows, cols, offsets, counts, srcs);
    k_gemm    <<<(NN + BM - 1) / BM, 256, 0, stream>>>(x, W, dinv, g);
    k_aggregate<<<(int)(((size_t)NN * 32 + 255) / 256), 256, 0, stream>>>(
        offsets, srcs, g, dinv, b, out);
}

// Round 9
// 297.115 us; speedup vs baseline: 6.3327x; 1.0851x over previous
//
#include <hip/hip_runtime.h>

#define NN 50000
#define NE 1000000
#define KF 256      // IN_FEAT
#define HD 128      // HIDDEN
#define NBLK ((NN + 255) / 256)   // 196 scan blocks

typedef unsigned short ushort_t;

// bf16 helpers (round-to-nearest-even pack, exact unpack)
__device__ __forceinline__ ushort_t f2bf(float f) {
    unsigned int u = __float_as_uint(f);
    u = (u + 0x7fffu + ((u >> 16) & 1u)) >> 16;
    return (ushort_t)u;
}
__device__ __forceinline__ float bf2f(ushort_t h) {
    return __uint_as_float(((unsigned int)h) << 16);
}

// ---------------- workspace layout (see kernel_launch) ----------------
// g       : NN*HD bf16    (h * dinv[row], rounded to bf16)
// dinv    : NN floats
// counts  : NN ints        (histogram, then reused as fill cursor)
// offsets : NN+1 ints      (CSR row pointers by destination)
// srcs    : NE ints        (edge sources, bucketed by destination)
// bsum    : NBLK ints      (block sums for two-level scan)

__global__ __launch_bounds__(256) void k_count(const int* __restrict__ cols,
                                               int* __restrict__ counts) {
    int e = blockIdx.x * blockDim.x + threadIdx.x;
    if (e < NE) atomicAdd(&counts[cols[e]], 1);
}

// ---- two-level scan: blocksum -> scan block sums -> per-block offsets ----
__global__ __launch_bounds__(256) void k_blocksum(const int* __restrict__ counts,
                                                  int* __restrict__ bsum) {
    __shared__ int red[256];
    int t = threadIdx.x;
    int i = blockIdx.x * 256 + t;
    red[t] = (i < NN) ? counts[i] : 0;
    __syncthreads();
    #pragma unroll
    for (int off = 128; off > 0; off >>= 1) {
        if (t < off) red[t] += red[t + off];
        __syncthreads();
    }
    if (t == 0) bsum[blockIdx.x] = red[0];
}

__global__ __launch_bounds__(256) void k_scanb(int* __restrict__ bsum) {
    __shared__ int part[256];
    int t = threadIdx.x;
    part[t] = (t < NBLK) ? bsum[t] : 0;
    __syncthreads();
    #pragma unroll
    for (int off = 1; off < 256; off <<= 1) {
        int v = (t >= off) ? part[t - off] : 0;
        __syncthreads();
        part[t] += v;
        __syncthreads();
    }
    if (t < NBLK) bsum[t] = (t > 0) ? part[t - 1] : 0;  // exclusive
}

__global__ __launch_bounds__(256) void k_offsets(int* __restrict__ counts,
                                                 const int* __restrict__ bsum,
                                                 int* __restrict__ offsets,
                                                 float* __restrict__ dinv) {
    __shared__ int part[256];
    int t = threadIdx.x;
    int i = blockIdx.x * 256 + t;
    int c = (i < NN) ? counts[i] : 0;
    part[t] = c;
    __syncthreads();
    #pragma unroll
    for (int off = 1; off < 256; off <<= 1) {
        int v = (t >= off) ? part[t - off] : 0;
        __syncthreads();
        part[t] += v;
        __syncthreads();
    }
    if (i < NN) {
        int excl = part[t] - c;  // inclusive - self
        offsets[i] = bsum[blockIdx.x] + excl;
        dinv[i] = rsqrtf((float)(c + 1));   // +1 self-loop
        counts[i] = 0;                       // reset cursor for k_fill
    }
    if (i == 0) offsets[NN] = NE;            // total is the known constant
}

__global__ __launch_bounds__(256) void k_fill(const int* __restrict__ rows,
                                              const int* __restrict__ cols,
                                              const int* __restrict__ offsets,
                                              int* __restrict__ cursor,
                                              int* __restrict__ srcs) {
    int e = blockIdx.x * blockDim.x + threadIdx.x;
    if (e >= NE) return;
    int c = cols[e];
    int slot = atomicAdd(&cursor[c], 1);
    srcs[offsets[c] + slot] = rows[e];
}

// GEMM: g[r][c] = bf16( dinv[r] * sum_k x[r][k] * W[k][c] )
// Block computes 64 rows x 128 cols; 256 threads; thread tile 8x4.
#define BM 64
#define BK 32

__global__ __launch_bounds__(256) void k_gemm(const float* __restrict__ x,
                                              const float* __restrict__ W,
                                              const float* __restrict__ dinv,
                                              ushort_t* __restrict__ g) {
    __shared__ __align__(16) float sx[BK][BM + 1];  // x tile, transposed
    __shared__ __align__(16) float sw[BK][HD];      // W tile

    const int tid = threadIdx.x;
    const int bm0 = blockIdx.x * BM;
    const int tx = tid & 31;   // col quad 0..31 -> cols tx*4..tx*4+3
    const int ty = tid >> 5;   // row group 0..7 -> rows ty*8..ty*8+7

    float acc[8][4] = {};

    for (int k0 = 0; k0 < KF; k0 += BK) {
        #pragma unroll
        for (int l = 0; l < 2; ++l) {
            int idx = tid + l * 256;
            int r  = idx >> 3;
            int kq = idx & 7;
            int grow = bm0 + r;
            float4 v = make_float4(0.f, 0.f, 0.f, 0.f);
            if (grow < NN)
                v = *(const float4*)(&x[(size_t)grow * KF + k0 + kq * 4]);
            sx[kq * 4 + 0][r] = v.x;
            sx[kq * 4 + 1][r] = v.y;
            sx[kq * 4 + 2][r] = v.z;
            sx[kq * 4 + 3][r] = v.w;
        }
        #pragma unroll
        for (int l = 0; l < 4; ++l) {
            int idx = tid + l * 256;
            int kr = idx >> 5;
            int cq = idx & 31;
            *(float4*)(&sw[kr][cq * 4]) =
                *(const float4*)(&W[(size_t)(k0 + kr) * HD + cq * 4]);
        }
        __syncthreads();

        #pragma unroll
        for (int kk = 0; kk < BK; ++kk) {
            float xv[8];
            #pragma unroll
            for (int i = 0; i < 8; ++i) xv[i] = sx[kk][ty * 8 + i];
            float4 wv = *(const float4*)(&sw[kk][tx * 4]);
            #pragma unroll
            for (int i = 0; i < 8; ++i) {
                acc[i][0] += xv[i] * wv.x;
                acc[i][1] += xv[i] * wv.y;
                acc[i][2] += xv[i] * wv.z;
                acc[i][3] += xv[i] * wv.w;
            }
        }
        __syncthreads();
    }

    #pragma unroll
    for (int i = 0; i < 8; ++i) {
        int grow = bm0 + ty * 8 + i;
        if (grow < NN) {
            float s = dinv[grow];
            ushort4 o;
            o.x = f2bf(acc[i][0] * s);
            o.y = f2bf(acc[i][1] * s);
            o.z = f2bf(acc[i][2] * s);
            o.w = f2bf(acc[i][3] * s);
            *(ushort4*)(&g[(size_t)grow * HD + tx * 4]) = o;
        }
    }
}

// Gather-reduce: 32 lanes per node; out[c] = b + dinv[c]*(g[c] + sum_in g[src])
__global__ __launch_bounds__(256) void k_aggregate(const int* __restrict__ offsets,
                                                   const int* __restrict__ srcs,
                                                   const ushort_t* __restrict__ g,
                                                   const float* __restrict__ dinv,
                                                   const float* __restrict__ b,
                                                   float* __restrict__ out) {
    int t = blockIdx.x * blockDim.x + threadIdx.x;
    int c    = t >> 5;
    int lane = t & 31;
    if (c >= NN) return;
    const int s0 = offsets[c];
    const int s1 = offsets[c + 1];

    // self-loop message: g[c] (norm dinv[c]*dinv[c], one factor folded below)
    ushort4 sv = *(const ushort4*)(&g[(size_t)c * HD + lane * 4]);
    float4 acc = make_float4(bf2f(sv.x), bf2f(sv.y), bf2f(sv.z), bf2f(sv.w));

    int s = s0;
    for (; s + 1 < s1; s += 2) {  // 2-way unroll for load-latency overlap
        int r0 = srcs[s];
        int r1 = srcs[s + 1];
        ushort4 a0 = *(const ushort4*)(&g[(size_t)r0 * HD + lane * 4]);
        ushort4 a1 = *(const ushort4*)(&g[(size_t)r1 * HD + lane * 4]);
        acc.x += bf2f(a0.x); acc.y += bf2f(a0.y);
        acc.z += bf2f(a0.z); acc.w += bf2f(a0.w);
        acc.x += bf2f(a1.x); acc.y += bf2f(a1.y);
        acc.z += bf2f(a1.z); acc.w += bf2f(a1.w);
    }
    if (s < s1) {
        int r0 = srcs[s];
        ushort4 a0 = *(const ushort4*)(&g[(size_t)r0 * HD + lane * 4]);
        acc.x += bf2f(a0.x); acc.y += bf2f(a0.y);
        acc.z += bf2f(a0.z); acc.w += bf2f(a0.w);
    }

    float sc = dinv[c];
    float4 bv = *(const float4*)(&b[lane * 4]);
    float4 o = make_float4(bv.x + sc * acc.x, bv.y + sc * acc.y,
                           bv.z + sc * acc.z, bv.w + sc * acc.w);
    *(float4*)(&out[(size_t)c * HD + lane * 4]) = o;
}

extern "C" void kernel_launch(void* const* d_in, const int* in_sizes, int n_in,
                              void* d_out, int out_size, void* d_ws, size_t ws_size,
                              hipStream_t stream) {
    const float* x  = (const float*)d_in[0];
    const int*   ei = (const int*)d_in[1];   // [2][NE]: rows then cols
    const float* W  = (const float*)d_in[2];
    const float* b  = (const float*)d_in[3];
    float* out = (float*)d_out;

    ushort_t* g    = (ushort_t*)d_ws;                    // NN*HD bf16
    float* dinv    = (float*)(g + (size_t)NN * HD);      // NN
    int*   counts  = (int*)(dinv + NN);                  // NN
    int*   offsets = counts + NN;                        // NN+1
    int*   srcs    = offsets + NN + 1;                   // NE
    int*   bsum    = srcs + NE;                          // NBLK

    const int* rows = ei;
    const int* cols = ei + NE;

    hipMemsetAsync(counts, 0, NN * sizeof(int), stream);
    k_count   <<<(NE + 255) / 256, 256, 0, stream>>>(cols, counts);
    k_blocksum<<<NBLK, 256, 0, stream>>>(counts, bsum);
    k_scanb   <<<1, 256, 0, stream>>>(bsum);
    k_offsets <<<NBLK, 256, 0, stream>>>(counts, bsum, offsets, dinv);
    k_fill    <<<(NE + 255) / 256, 256, 0, stream>>>(rows, cols, offsets, counts, srcs);
    k_gemm    <<<(NN + BM - 1) / BM, 256, 0, stream>>>(x, W, dinv, g);
    k_aggregate<<<(int)(((size_t)NN * 32 + 255) / 256), 256, 0, stream>>>(
        offsets, srcs, g, dinv, b, out);
}

// Round 13
// 253.492 us; speedup vs baseline: 7.4225x; 1.1721x over previous
//
#include <hip/hip_runtime.h>

#define NN 50000
#define NE 1000000
#define KF 256      // IN_FEAT
#define HD 128      // HIDDEN
#define NBLK ((NN + 255) / 256)   // 196 scan blocks

typedef unsigned short ushort_t;
typedef __attribute__((ext_vector_type(8))) short short8_t;  // 8 bf16 (4 VGPRs)
typedef __attribute__((ext_vector_type(4))) float f32x4;     // MFMA C/D

// bf16 helpers (round-to-nearest-even pack, exact unpack)
__device__ __forceinline__ ushort_t f2bf(float f) {
    unsigned int u = __float_as_uint(f);
    u = (u + 0x7fffu + ((u >> 16) & 1u)) >> 16;
    return (ushort_t)u;
}
__device__ __forceinline__ float bf2f(ushort_t h) {
    return __uint_as_float(((unsigned int)h) << 16);
}

// ---------------- workspace layout (see kernel_launch) ----------------
// g       : NN*HD bf16    (h * dinv[row], rounded to bf16)
// dinv    : NN floats
// counts  : NN ints        (histogram, then reused as fill cursor)
// offsets : NN+1 ints      (CSR row pointers by destination)
// bsum    : NBLK ints      (block sums for two-level scan)
// Wt      : HD*KF bf16     (W transposed, K-contiguous, for MFMA)
// srcs    : NE ushort      (edge sources, bucketed by destination; NN<65536)

__global__ __launch_bounds__(256) void k_count(const int* __restrict__ cols,
                                               int* __restrict__ counts) {
    int e = blockIdx.x * blockDim.x + threadIdx.x;
    if (e < NE) atomicAdd(&counts[cols[e]], 1);
}

// ---- two-level scan: blocksum -> scan block sums -> per-block offsets ----
__global__ __launch_bounds__(256) void k_blocksum(const int* __restrict__ counts,
                                                  int* __restrict__ bsum) {
    __shared__ int red[256];
    int t = threadIdx.x;
    int i = blockIdx.x * 256 + t;
    red[t] = (i < NN) ? counts[i] : 0;
    __syncthreads();
    #pragma unroll
    for (int off = 128; off > 0; off >>= 1) {
        if (t < off) red[t] += red[t + off];
        __syncthreads();
    }
    if (t == 0) bsum[blockIdx.x] = red[0];
}

__global__ __launch_bounds__(256) void k_scanb(int* __restrict__ bsum) {
    __shared__ int part[256];
    int t = threadIdx.x;
    part[t] = (t < NBLK) ? bsum[t] : 0;
    __syncthreads();
    #pragma unroll
    for (int off = 1; off < 256; off <<= 1) {
        int v = (t >= off) ? part[t - off] : 0;
        __syncthreads();
        part[t] += v;
        __syncthreads();
    }
    if (t < NBLK) bsum[t] = (t > 0) ? part[t - 1] : 0;  // exclusive
}

__global__ __launch_bounds__(256) void k_offsets(int* __restrict__ counts,
                                                 const int* __restrict__ bsum,
                                                 int* __restrict__ offsets,
                                                 float* __restrict__ dinv) {
    __shared__ int part[256];
    int t = threadIdx.x;
    int i = blockIdx.x * 256 + t;
    int c = (i < NN) ? counts[i] : 0;
    part[t] = c;
    __syncthreads();
    #pragma unroll
    for (int off = 1; off < 256; off <<= 1) {
        int v = (t >= off) ? part[t - off] : 0;
        __syncthreads();
        part[t] += v;
        __syncthreads();
    }
    if (i < NN) {
        int excl = part[t] - c;  // inclusive - self
        offsets[i] = bsum[blockIdx.x] + excl;
        dinv[i] = rsqrtf((float)(c + 1));   // +1 self-loop
        counts[i] = 0;                       // reset cursor for k_fill
    }
    if (i == 0) offsets[NN] = NE;            // total is the known constant
}

__global__ __launch_bounds__(256) void k_fill(const int* __restrict__ rows,
                                              const int* __restrict__ cols,
                                              const int* __restrict__ offsets,
                                              int* __restrict__ cursor,
                                              ushort_t* __restrict__ srcs) {
    int e = blockIdx.x * blockDim.x + threadIdx.x;
    if (e >= NE) return;
    int c = cols[e];
    int slot = atomicAdd(&cursor[c], 1);
    srcs[offsets[c] + slot] = (ushort_t)rows[e];
}

// W transpose to bf16 K-contiguous: Wt[c][k] = bf16(W[k][c])
// grid 128 (one block per output col), block 256 (one thread per k)
__global__ __launch_bounds__(256) void k_wt(const float* __restrict__ W,
                                            ushort_t* __restrict__ Wt) {
    int k = threadIdx.x;   // 0..255
    int c = blockIdx.x;    // 0..127
    Wt[c * KF + k] = f2bf(W[(size_t)k * HD + c]);
}

// MFMA GEMM: g[r][c] = bf16( dinv[r] * sum_k x[r][k] * W[k][c] )
// Block: 256 threads = 4 waves; 64 rows x 128 cols. Wave w: rows w*16..w*16+15.
// LDS: half of Wt (128 cols x 128 k) bf16, XOR-swizzled, per K-phase (32 KB).
__global__ __launch_bounds__(256) void k_gemm(const float* __restrict__ x,
                                              const ushort_t* __restrict__ Wt,
                                              const float* __restrict__ dinv,
                                              ushort_t* __restrict__ g) {
    __shared__ __align__(16) ushort_t sW[128 * 128];  // 32 KB, swizzled

    const int tid  = threadIdx.x;
    const int wave = tid >> 6;      // 0..3
    const int lane = tid & 63;
    const int l15  = lane & 15;
    const int lhi  = lane >> 4;     // 0..3
    const int bm0  = blockIdx.x * 64;
    const int row  = bm0 + wave * 16 + l15;   // A-operand row
    const bool rok = row < NN;

    f32x4 acc[8];
    #pragma unroll
    for (int n = 0; n < 8; ++n) acc[n] = (f32x4){0.f, 0.f, 0.f, 0.f};

    for (int p = 0; p < 2; ++p) {
        // stage K-half p: 128 cols x 128 k bf16 = 32768 B, 16 B per thread-iter
        #pragma unroll
        for (int it = 0; it < 8; ++it) {
            int Lb  = (it * 256 + tid) * 16;   // linear byte in half-tile
            int c   = Lb >> 8;                 // 256 B per half-row
            int ofs = Lb & 255;
            short8_t v = *(const short8_t*)((const char*)Wt +
                                            (size_t)c * 512 + p * 256 + ofs);
            *(short8_t*)((char*)sW + c * 256 + (ofs ^ ((c & 7) << 4))) = v;
        }
        __syncthreads();

        #pragma unroll
        for (int kk = 0; kk < 4; ++kk) {
            // A frag: x[row][p*128 + kk*32 + lhi*8 .. +7] -> bf16x8
            short8_t a = {0, 0, 0, 0, 0, 0, 0, 0};
            if (rok) {
                const float* xp = &x[(size_t)row * KF + p * 128 + kk * 32 + lhi * 8];
                float4 x0 = *(const float4*)(xp);
                float4 x1 = *(const float4*)(xp + 4);
                a[0] = (short)f2bf(x0.x); a[1] = (short)f2bf(x0.y);
                a[2] = (short)f2bf(x0.z); a[3] = (short)f2bf(x0.w);
                a[4] = (short)f2bf(x1.x); a[5] = (short)f2bf(x1.y);
                a[6] = (short)f2bf(x1.z); a[7] = (short)f2bf(x1.w);
            }
            const int kl = kk * 64 + lhi * 16;  // local k byte offset
            #pragma unroll
            for (int n = 0; n < 8; ++n) {
                int c = n * 16 + l15;
                short8_t b = *(const short8_t*)((const char*)sW +
                                                c * 256 + (kl ^ ((c & 7) << 4)));
                acc[n] = __builtin_amdgcn_mfma_f32_16x16x32_bf16(a, b, acc[n], 0, 0, 0);
            }
        }
        __syncthreads();
    }

    // D: lane reg r -> row (lhi*4 + r), col (n*16 + l15)   [m89 C/D mapping]
    const int orow = bm0 + wave * 16 + lhi * 4;
    #pragma unroll
    for (int r = 0; r < 4; ++r) {
        int gr = orow + r;
        if (gr < NN) {
            float s = dinv[gr];
            #pragma unroll
            for (int n = 0; n < 8; ++n)
                g[(size_t)gr * HD + n * 16 + l15] = f2bf(acc[n][r] * s);
        }
    }
}

// Gather-reduce: 32 lanes per node; out[c] = b + dinv[c]*(g[c] + sum_in g[src])
__global__ __launch_bounds__(256) void k_aggregate(const int* __restrict__ offsets,
                                                   const ushort_t* __restrict__ srcs,
                                                   const ushort_t* __restrict__ g,
                                                   const float* __restrict__ dinv,
                                                   const float* __restrict__ b,
                                                   float* __restrict__ out) {
    int t = blockIdx.x * blockDim.x + threadIdx.x;
    int c    = t >> 5;
    int lane = t & 31;
    if (c >= NN) return;
    const int s0 = offsets[c];
    const int s1 = offsets[c + 1];

    // self-loop message: g[c] (norm dinv[c]*dinv[c], one factor folded below)
    ushort4 sv = *(const ushort4*)(&g[(size_t)c * HD + lane * 4]);
    float4 acc = make_float4(bf2f(sv.x), bf2f(sv.y), bf2f(sv.z), bf2f(sv.w));

    int s = s0;
    for (; s + 1 < s1; s += 2) {  // 2-way unroll for load-latency overlap
        int r0 = srcs[s];
        int r1 = srcs[s + 1];
        ushort4 a0 = *(const ushort4*)(&g[(size_t)r0 * HD + lane * 4]);
        ushort4 a1 = *(const ushort4*)(&g[(size_t)r1 * HD + lane * 4]);
        acc.x += bf2f(a0.x); acc.y += bf2f(a0.y);
        acc.z += bf2f(a0.z); acc.w += bf2f(a0.w);
        acc.x += bf2f(a1.x); acc.y += bf2f(a1.y);
        acc.z += bf2f(a1.z); acc.w += bf2f(a1.w);
    }
    if (s < s1) {
        int r0 = srcs[s];
        ushort4 a0 = *(const ushort4*)(&g[(size_t)r0 * HD + lane * 4]);
        acc.x += bf2f(a0.x); acc.y += bf2f(a0.y);
        acc.z += bf2f(a0.z); acc.w += bf2f(a0.w);
    }

    float sc = dinv[c];
    float4 bv = *(const float4*)(&b[lane * 4]);
    float4 o = make_float4(bv.x + sc * acc.x, bv.y + sc * acc.y,
                           bv.z + sc * acc.z, bv.w + sc * acc.w);
    *(float4*)(&out[(size_t)c * HD + lane * 4]) = o;
}

extern "C" void kernel_launch(void* const* d_in, const int* in_sizes, int n_in,
                              void* d_out, int out_size, void* d_ws, size_t ws_size,
                              hipStream_t stream) {
    const float* x  = (const float*)d_in[0];
    const int*   ei = (const int*)d_in[1];   // [2][NE]: rows then cols
    const float* W  = (const float*)d_in[2];
    const float* b  = (const float*)d_in[3];
    float* out = (float*)d_out;

    ushort_t* g    = (ushort_t*)d_ws;                    // NN*HD bf16
    float* dinv    = (float*)(g + (size_t)NN * HD);      // NN
    int*   counts  = (int*)(dinv + NN);                  // NN
    int*   offsets = counts + NN;                        // NN+1
    int*   bsum    = offsets + NN + 1;                   // NBLK
    size_t wtoff   = (((size_t)((char*)(bsum + NBLK) - (char*)d_ws)) + 15) & ~(size_t)15;
    ushort_t* Wt   = (ushort_t*)((char*)d_ws + wtoff);   // HD*KF bf16 (16B aligned)
    ushort_t* srcs = Wt + (size_t)HD * KF;               // NE ushort

    const int* rows = ei;
    const int* cols = ei + NE;

    hipMemsetAsync(counts, 0, NN * sizeof(int), stream);
    k_wt      <<<HD, 256, 0, stream>>>(W, Wt);
    k_count   <<<(NE + 255) / 256, 256, 0, stream>>>(cols, counts);
    k_blocksum<<<NBLK, 256, 0, stream>>>(counts, bsum);
    k_scanb   <<<1, 256, 0, stream>>>(bsum);
    k_offsets <<<NBLK, 256, 0, stream>>>(counts, bsum, offsets, dinv);
    k_fill    <<<(NE + 255) / 256, 256, 0, stream>>>(rows, cols, offsets, counts, srcs);
    k_gemm    <<<(NN + 63) / 64, 256, 0, stream>>>(x, Wt, dinv, g);
    k_aggregate<<<(int)(((size_t)NN * 32 + 255) / 256), 256, 0, stream>>>(
        offsets, srcs, g, dinv, b, out);
}

// Round 14
// 214.900 us; speedup vs baseline: 8.7554x; 1.1796x over previous
//
#include <hip/hip_runtime.h>

#define NN 50000
#define NE 1000000
#define KF 256      // IN_FEAT
#define HD 128      // HIDDEN
#define NBLK ((NN + 255) / 256)   // 196 scan blocks

typedef unsigned short ushort_t;
typedef __attribute__((ext_vector_type(8))) short short8_t;  // 8 bf16 (4 VGPRs)
typedef __attribute__((ext_vector_type(4))) float f32x4;     // MFMA C/D

// bf16 helpers (round-to-nearest-even pack, exact unpack)
__device__ __forceinline__ ushort_t f2bf(float f) {
    unsigned int u = __float_as_uint(f);
    u = (u + 0x7fffu + ((u >> 16) & 1u)) >> 16;
    return (ushort_t)u;
}
__device__ __forceinline__ float bf2f(ushort_t h) {
    return __uint_as_float(((unsigned int)h) << 16);
}

// ---------------- workspace layout (see kernel_launch) ----------------
// g       : NN*HD bf16    (h * dinv[row], rounded to bf16)
// dinv    : NN floats
// counts  : NN ints        (histogram via k_slots)
// offsets : NN+1 ints      (CSR row pointers by destination)
// bsum    : NBLK ints      (block sums for two-level scan)
// Wt      : HD*KF bf16     (W transposed, K-contiguous, for MFMA)
// srcs    : NE ushort      (edge sources, bucketed by destination; NN<65536)
// aux     : NE ushort      (within-bucket slot per edge, from k_slots)

// Pass 1: histogram + record each edge's within-bucket slot (coalesced write).
// Breaks the atomic->scattered-store dependency that stalled the old k_fill.
__global__ __launch_bounds__(256) void k_slots(const int* __restrict__ cols,
                                               int* __restrict__ counts,
                                               ushort_t* __restrict__ aux) {
    int e = blockIdx.x * blockDim.x + threadIdx.x;
    if (e >= NE) return;
    int slot = atomicAdd(&counts[cols[e]], 1);
    aux[e] = (ushort_t)slot;
}

// ---- two-level scan: blocksum -> scan block sums -> per-block offsets ----
__global__ __launch_bounds__(256) void k_blocksum(const int* __restrict__ counts,
                                                  int* __restrict__ bsum) {
    __shared__ int red[256];
    int t = threadIdx.x;
    int i = blockIdx.x * 256 + t;
    red[t] = (i < NN) ? counts[i] : 0;
    __syncthreads();
    #pragma unroll
    for (int off = 128; off > 0; off >>= 1) {
        if (t < off) red[t] += red[t + off];
        __syncthreads();
    }
    if (t == 0) bsum[blockIdx.x] = red[0];
}

__global__ __launch_bounds__(256) void k_scanb(int* __restrict__ bsum) {
    __shared__ int part[256];
    int t = threadIdx.x;
    part[t] = (t < NBLK) ? bsum[t] : 0;
    __syncthreads();
    #pragma unroll
    for (int off = 1; off < 256; off <<= 1) {
        int v = (t >= off) ? part[t - off] : 0;
        __syncthreads();
        part[t] += v;
        __syncthreads();
    }
    if (t < NBLK) bsum[t] = (t > 0) ? part[t - 1] : 0;  // exclusive
}

__global__ __launch_bounds__(256) void k_offsets(const int* __restrict__ counts,
                                                 const int* __restrict__ bsum,
                                                 int* __restrict__ offsets,
                                                 float* __restrict__ dinv) {
    __shared__ int part[256];
    int t = threadIdx.x;
    int i = blockIdx.x * 256 + t;
    int c = (i < NN) ? counts[i] : 0;
    part[t] = c;
    __syncthreads();
    #pragma unroll
    for (int off = 1; off < 256; off <<= 1) {
        int v = (t >= off) ? part[t - off] : 0;
        __syncthreads();
        part[t] += v;
        __syncthreads();
    }
    if (i < NN) {
        int excl = part[t] - c;  // inclusive - self
        offsets[i] = bsum[blockIdx.x] + excl;
        dinv[i] = rsqrtf((float)(c + 1));   // +1 self-loop
    }
    if (i == 0) offsets[NN] = NE;            // total is the known constant
}

// Pass 2: pure scatter, no atomics — stores are independent, fully pipelined.
__global__ __launch_bounds__(256) void k_fill(const int* __restrict__ rows,
                                              const int* __restrict__ cols,
                                              const int* __restrict__ offsets,
                                              const ushort_t* __restrict__ aux,
                                              ushort_t* __restrict__ srcs) {
    int e = blockIdx.x * blockDim.x + threadIdx.x;
    if (e >= NE) return;
    int c = cols[e];
    srcs[offsets[c] + (int)aux[e]] = (ushort_t)rows[e];
}

// W transpose to bf16 K-contiguous: Wt[c][k] = bf16(W[k][c])
// grid 128 (one block per output col), block 256 (one thread per k)
__global__ __launch_bounds__(256) void k_wt(const float* __restrict__ W,
                                            ushort_t* __restrict__ Wt) {
    int k = threadIdx.x;   // 0..255
    int c = blockIdx.x;    // 0..127
    Wt[c * KF + k] = f2bf(W[(size_t)k * HD + c]);
}

// MFMA GEMM: g[r][c] = bf16( dinv[r] * sum_k x[r][k] * W[k][c] )
// Block: 256 threads = 4 waves; 64 rows x 128 cols. Wave w: rows w*16..w*16+15.
// LDS: half of Wt (128 cols x 128 k) bf16, XOR-swizzled, per K-phase (32 KB).
__global__ __launch_bounds__(256) void k_gemm(const float* __restrict__ x,
                                              const ushort_t* __restrict__ Wt,
                                              const float* __restrict__ dinv,
                                              ushort_t* __restrict__ g) {
    __shared__ __align__(16) ushort_t sW[128 * 128];  // 32 KB, swizzled

    const int tid  = threadIdx.x;
    const int wave = tid >> 6;      // 0..3
    const int lane = tid & 63;
    const int l15  = lane & 15;
    const int lhi  = lane >> 4;     // 0..3
    const int bm0  = blockIdx.x * 64;
    const int row  = bm0 + wave * 16 + l15;   // A-operand row
    const bool rok = row < NN;

    f32x4 acc[8];
    #pragma unroll
    for (int n = 0; n < 8; ++n) acc[n] = (f32x4){0.f, 0.f, 0.f, 0.f};

    for (int p = 0; p < 2; ++p) {
        // stage K-half p: 128 cols x 128 k bf16 = 32768 B, 16 B per thread-iter
        #pragma unroll
        for (int it = 0; it < 8; ++it) {
            int Lb  = (it * 256 + tid) * 16;   // linear byte in half-tile
            int c   = Lb >> 8;                 // 256 B per half-row
            int ofs = Lb & 255;
            short8_t v = *(const short8_t*)((const char*)Wt +
                                            (size_t)c * 512 + p * 256 + ofs);
            *(short8_t*)((char*)sW + c * 256 + (ofs ^ ((c & 7) << 4))) = v;
        }
        __syncthreads();

        #pragma unroll
        for (int kk = 0; kk < 4; ++kk) {
            // A frag: x[row][p*128 + kk*32 + lhi*8 .. +7] -> bf16x8
            short8_t a = {0, 0, 0, 0, 0, 0, 0, 0};
            if (rok) {
                const float* xp = &x[(size_t)row * KF + p * 128 + kk * 32 + lhi * 8];
                float4 x0 = *(const float4*)(xp);
                float4 x1 = *(const float4*)(xp + 4);
                a[0] = (short)f2bf(x0.x); a[1] = (short)f2bf(x0.y);
                a[2] = (short)f2bf(x0.z); a[3] = (short)f2bf(x0.w);
                a[4] = (short)f2bf(x1.x); a[5] = (short)f2bf(x1.y);
                a[6] = (short)f2bf(x1.z); a[7] = (short)f2bf(x1.w);
            }
            const int kl = kk * 64 + lhi * 16;  // local k byte offset
            #pragma unroll
            for (int n = 0; n < 8; ++n) {
                int c = n * 16 + l15;
                short8_t b = *(const short8_t*)((const char*)sW +
                                                c * 256 + (kl ^ ((c & 7) << 4)));
                acc[n] = __builtin_amdgcn_mfma_f32_16x16x32_bf16(a, b, acc[n], 0, 0, 0);
            }
        }
        __syncthreads();
    }

    // D: lane reg r -> row (lhi*4 + r), col (n*16 + l15)   [m89 C/D mapping]
    const int orow = bm0 + wave * 16 + lhi * 4;
    #pragma unroll
    for (int r = 0; r < 4; ++r) {
        int gr = orow + r;
        if (gr < NN) {
            float s = dinv[gr];
            #pragma unroll
            for (int n = 0; n < 8; ++n)
                g[(size_t)gr * HD + n * 16 + l15] = f2bf(acc[n][r] * s);
        }
    }
}

// Gather-reduce: 32 lanes per node; out[c] = b + dinv[c]*(g[c] + sum_in g[src])
__global__ __launch_bounds__(256) void k_aggregate(const int* __restrict__ offsets,
                                                   const ushort_t* __restrict__ srcs,
                                                   const ushort_t* __restrict__ g,
                                                   const float* __restrict__ dinv,
                                                   const float* __restrict__ b,
                                                   float* __restrict__ out) {
    int t = blockIdx.x * blockDim.x + threadIdx.x;
    int c    = t >> 5;
    int lane = t & 31;
    if (c >= NN) return;
    const int s0 = offsets[c];
    const int s1 = offsets[c + 1];

    // self-loop message: g[c] (norm dinv[c]*dinv[c], one factor folded below)
    ushort4 sv = *(const ushort4*)(&g[(size_t)c * HD + lane * 4]);
    float4 acc = make_float4(bf2f(sv.x), bf2f(sv.y), bf2f(sv.z), bf2f(sv.w));

    int s = s0;
    for (; s + 1 < s1; s += 2) {  // 2-way unroll for load-latency overlap
        int r0 = srcs[s];
        int r1 = srcs[s + 1];
        ushort4 a0 = *(const ushort4*)(&g[(size_t)r0 * HD + lane * 4]);
        ushort4 a1 = *(const ushort4*)(&g[(size_t)r1 * HD + lane * 4]);
        acc.x += bf2f(a0.x); acc.y += bf2f(a0.y);
        acc.z += bf2f(a0.z); acc.w += bf2f(a0.w);
        acc.x += bf2f(a1.x); acc.y += bf2f(a1.y);
        acc.z += bf2f(a1.z); acc.w += bf2f(a1.w);
    }
    if (s < s1) {
        int r0 = srcs[s];
        ushort4 a0 = *(const ushort4*)(&g[(size_t)r0 * HD + lane * 4]);
        acc.x += bf2f(a0.x); acc.y += bf2f(a0.y);
        acc.z += bf2f(a0.z); acc.w += bf2f(a0.w);
    }

    float sc = dinv[c];
    float4 bv = *(const float4*)(&b[lane * 4]);
    float4 o = make_float4(bv.x + sc * acc.x, bv.y + sc * acc.y,
                           bv.z + sc * acc.z, bv.w + sc * acc.w);
    *(float4*)(&out[(size_t)c * HD + lane * 4]) = o;
}

extern "C" void kernel_launch(void* const* d_in, const int* in_sizes, int n_in,
                              void* d_out, int out_size, void* d_ws, size_t ws_size,
                              hipStream_t stream) {
    const float* x  = (const float*)d_in[0];
    const int*   ei = (const int*)d_in[1];   // [2][NE]: rows then cols
    const float* W  = (const float*)d_in[2];
    const float* b  = (const float*)d_in[3];
    float* out = (float*)d_out;

    ushort_t* g    = (ushort_t*)d_ws;                    // NN*HD bf16
    float* dinv    = (float*)(g + (size_t)NN * HD);      // NN
    int*   counts  = (int*)(dinv + NN);                  // NN
    int*   offsets = counts + NN;                        // NN+1
    int*   bsum    = offsets + NN + 1;                   // NBLK
    size_t wtoff   = (((size_t)((char*)(bsum + NBLK) - (char*)d_ws)) + 15) & ~(size_t)15;
    ushort_t* Wt   = (ushort_t*)((char*)d_ws + wtoff);   // HD*KF bf16 (16B aligned)
    ushort_t* srcs = Wt + (size_t)HD * KF;               // NE ushort
    ushort_t* aux  = srcs + NE;                          // NE ushort

    const int* rows = ei;
    const int* cols = ei + NE;

    hipMemsetAsync(counts, 0, NN * sizeof(int), stream);
    k_wt      <<<HD, 256, 0, stream>>>(W, Wt);
    k_slots   <<<(NE + 255) / 256, 256, 0, stream>>>(cols, counts, aux);
    k_blocksum<<<NBLK, 256, 0, stream>>>(counts, bsum);
    k_scanb   <<<1, 256, 0, stream>>>(bsum);
    k_offsets <<<NBLK, 256, 0, stream>>>(counts, bsum, offsets, dinv);
    k_fill    <<<(NE + 255) / 256, 256, 0, stream>>>(rows, cols, offsets, aux, srcs);
    k_gemm    <<<(NN + 63) / 64, 256, 0, stream>>>(x, Wt, dinv, g);
    k_aggregate<<<(int)(((size_t)NN * 32 + 255) / 256), 256, 0, stream>>>(
        offsets, srcs, g, dinv, b, out);
}

// Round 15
// 211.505 us; speedup vs baseline: 8.8959x; 1.0161x over previous
//
#include <hip/hip_runtime.h>

#define NN 50000
#define NE 1000000
#define KF 256      // IN_FEAT
#define HD 128      // HIDDEN
#define NBLK ((NN + 255) / 256)   // 196 scan blocks

typedef unsigned short ushort_t;
typedef __attribute__((ext_vector_type(8))) short short8_t;            // 8 bf16
typedef __attribute__((ext_vector_type(8))) unsigned short ushort8_t;  // 8 bf16 bits
typedef __attribute__((ext_vector_type(4))) float f32x4;               // MFMA C/D

// bf16 helpers (round-to-nearest-even pack, exact unpack)
__device__ __forceinline__ ushort_t f2bf(float f) {
    unsigned int u = __float_as_uint(f);
    u = (u + 0x7fffu + ((u >> 16) & 1u)) >> 16;
    return (ushort_t)u;
}
__device__ __forceinline__ float bf2f(ushort_t h) {
    return __uint_as_float(((unsigned int)h) << 16);
}

// ---------------- workspace layout (see kernel_launch) ----------------
// g       : NN*HD bf16    (h * dinv[row], rounded to bf16)
// dinv    : NN floats
// counts  : NN ints        (histogram via k_slots)
// offsets : NN+1 ints      (CSR row pointers by destination)
// bsum    : NBLK ints      (block sums for two-level scan)
// Wt      : HD*KF bf16     (W transposed, K-contiguous, for MFMA)
// srcs    : NE ushort      (edge sources, bucketed by destination; NN<65536)
// aux     : NE ushort      (within-bucket slot per edge, from k_slots)

// Pass 1: histogram + record each edge's within-bucket slot (coalesced write).
__global__ __launch_bounds__(256) void k_slots(const int* __restrict__ cols,
                                               int* __restrict__ counts,
                                               ushort_t* __restrict__ aux) {
    int e = blockIdx.x * blockDim.x + threadIdx.x;
    if (e >= NE) return;
    int slot = atomicAdd(&counts[cols[e]], 1);
    aux[e] = (ushort_t)slot;
}

// ---- two-level scan: blocksum -> scan block sums -> per-block offsets ----
__global__ __launch_bounds__(256) void k_blocksum(const int* __restrict__ counts,
                                                  int* __restrict__ bsum) {
    __shared__ int red[256];
    int t = threadIdx.x;
    int i = blockIdx.x * 256 + t;
    red[t] = (i < NN) ? counts[i] : 0;
    __syncthreads();
    #pragma unroll
    for (int off = 128; off > 0; off >>= 1) {
        if (t < off) red[t] += red[t + off];
        __syncthreads();
    }
    if (t == 0) bsum[blockIdx.x] = red[0];
}

__global__ __launch_bounds__(256) void k_scanb(int* __restrict__ bsum) {
    __shared__ int part[256];
    int t = threadIdx.x;
    part[t] = (t < NBLK) ? bsum[t] : 0;
    __syncthreads();
    #pragma unroll
    for (int off = 1; off < 256; off <<= 1) {
        int v = (t >= off) ? part[t - off] : 0;
        __syncthreads();
        part[t] += v;
        __syncthreads();
    }
    if (t < NBLK) bsum[t] = (t > 0) ? part[t - 1] : 0;  // exclusive
}

__global__ __launch_bounds__(256) void k_offsets(const int* __restrict__ counts,
                                                 const int* __restrict__ bsum,
                                                 int* __restrict__ offsets,
                                                 float* __restrict__ dinv) {
    __shared__ int part[256];
    int t = threadIdx.x;
    int i = blockIdx.x * 256 + t;
    int c = (i < NN) ? counts[i] : 0;
    part[t] = c;
    __syncthreads();
    #pragma unroll
    for (int off = 1; off < 256; off <<= 1) {
        int v = (t >= off) ? part[t - off] : 0;
        __syncthreads();
        part[t] += v;
        __syncthreads();
    }
    if (i < NN) {
        int excl = part[t] - c;  // inclusive - self
        offsets[i] = bsum[blockIdx.x] + excl;
        dinv[i] = rsqrtf((float)(c + 1));   // +1 self-loop
    }
    if (i == 0) offsets[NN] = NE;            // total is the known constant
}

// Pass 2: pure scatter, no atomics — stores are independent, fully pipelined.
__global__ __launch_bounds__(256) void k_fill(const int* __restrict__ rows,
                                              const int* __restrict__ cols,
                                              const int* __restrict__ offsets,
                                              const ushort_t* __restrict__ aux,
                                              ushort_t* __restrict__ srcs) {
    int e = blockIdx.x * blockDim.x + threadIdx.x;
    if (e >= NE) return;
    int c = cols[e];
    srcs[offsets[c] + (int)aux[e]] = (ushort_t)rows[e];
}

// W transpose to bf16 K-contiguous: Wt[c][k] = bf16(W[k][c])
__global__ __launch_bounds__(256) void k_wt(const float* __restrict__ W,
                                            ushort_t* __restrict__ Wt) {
    int k = threadIdx.x;   // 0..255
    int c = blockIdx.x;    // 0..127
    Wt[c * KF + k] = f2bf(W[(size_t)k * HD + c]);
}

// MFMA GEMM: g[r][c] = bf16( dinv[r] * sum_k x[r][k] * W[k][c] )
__global__ __launch_bounds__(256) void k_gemm(const float* __restrict__ x,
                                              const ushort_t* __restrict__ Wt,
                                              const float* __restrict__ dinv,
                                              ushort_t* __restrict__ g) {
    __shared__ __align__(16) ushort_t sW[128 * 128];  // 32 KB, swizzled

    const int tid  = threadIdx.x;
    const int wave = tid >> 6;      // 0..3
    const int lane = tid & 63;
    const int l15  = lane & 15;
    const int lhi  = lane >> 4;     // 0..3
    const int bm0  = blockIdx.x * 64;
    const int row  = bm0 + wave * 16 + l15;   // A-operand row
    const bool rok = row < NN;

    f32x4 acc[8];
    #pragma unroll
    for (int n = 0; n < 8; ++n) acc[n] = (f32x4){0.f, 0.f, 0.f, 0.f};

    for (int p = 0; p < 2; ++p) {
        #pragma unroll
        for (int it = 0; it < 8; ++it) {
            int Lb  = (it * 256 + tid) * 16;   // linear byte in half-tile
            int c   = Lb >> 8;                 // 256 B per half-row
            int ofs = Lb & 255;
            short8_t v = *(const short8_t*)((const char*)Wt +
                                            (size_t)c * 512 + p * 256 + ofs);
            *(short8_t*)((char*)sW + c * 256 + (ofs ^ ((c & 7) << 4))) = v;
        }
        __syncthreads();

        #pragma unroll
        for (int kk = 0; kk < 4; ++kk) {
            short8_t a = {0, 0, 0, 0, 0, 0, 0, 0};
            if (rok) {
                const float* xp = &x[(size_t)row * KF + p * 128 + kk * 32 + lhi * 8];
                float4 x0 = *(const float4*)(xp);
                float4 x1 = *(const float4*)(xp + 4);
                a[0] = (short)f2bf(x0.x); a[1] = (short)f2bf(x0.y);
                a[2] = (short)f2bf(x0.z); a[3] = (short)f2bf(x0.w);
                a[4] = (short)f2bf(x1.x); a[5] = (short)f2bf(x1.y);
                a[6] = (short)f2bf(x1.z); a[7] = (short)f2bf(x1.w);
            }
            const int kl = kk * 64 + lhi * 16;  // local k byte offset
            #pragma unroll
            for (int n = 0; n < 8; ++n) {
                int c = n * 16 + l15;
                short8_t b = *(const short8_t*)((const char*)sW +
                                                c * 256 + (kl ^ ((c & 7) << 4)));
                acc[n] = __builtin_amdgcn_mfma_f32_16x16x32_bf16(a, b, acc[n], 0, 0, 0);
            }
        }
        __syncthreads();
    }

    // D: lane reg r -> row (lhi*4 + r), col (n*16 + l15)   [m89 C/D mapping]
    const int orow = bm0 + wave * 16 + lhi * 4;
    #pragma unroll
    for (int r = 0; r < 4; ++r) {
        int gr = orow + r;
        if (gr < NN) {
            float s = dinv[gr];
            #pragma unroll
            for (int n = 0; n < 8; ++n)
                g[(size_t)gr * HD + n * 16 + l15] = f2bf(acc[n][r] * s);
        }
    }
}

// Gather-reduce: 16 lanes per node (lane owns 8 features, ushort8 = 16 B loads).
// 4 node-streams per wave x 2-way unroll = 8 outstanding gather segments/wave.
__global__ __launch_bounds__(256) void k_aggregate(const int* __restrict__ offsets,
                                                   const ushort_t* __restrict__ srcs,
                                                   const ushort_t* __restrict__ g,
                                                   const float* __restrict__ dinv,
                                                   const float* __restrict__ b,
                                                   float* __restrict__ out) {
    int t = blockIdx.x * blockDim.x + threadIdx.x;
    int c    = t >> 4;
    int lane = t & 15;       // feature block: lane*8 .. lane*8+7
    if (c >= NN) return;
    const int s0 = offsets[c];
    const int s1 = offsets[c + 1];

    // self-loop message: g[c]
    ushort8_t sv = *(const ushort8_t*)(&g[(size_t)c * HD + lane * 8]);
    float acc[8];
    #pragma unroll
    for (int j = 0; j < 8; ++j) acc[j] = bf2f(sv[j]);

    int s = s0;
    for (; s + 1 < s1; s += 2) {
        int r0 = srcs[s];
        int r1 = srcs[s + 1];
        ushort8_t a0 = *(const ushort8_t*)(&g[(size_t)r0 * HD + lane * 8]);
        ushort8_t a1 = *(const ushort8_t*)(&g[(size_t)r1 * HD + lane * 8]);
        #pragma unroll
        for (int j = 0; j < 8; ++j) acc[j] += bf2f(a0[j]) + bf2f(a1[j]);
    }
    if (s < s1) {
        int r0 = srcs[s];
        ushort8_t a0 = *(const ushort8_t*)(&g[(size_t)r0 * HD + lane * 8]);
        #pragma unroll
        for (int j = 0; j < 8; ++j) acc[j] += bf2f(a0[j]);
    }

    float sc = dinv[c];
    const float* bp = &b[lane * 8];
    float4 bv0 = *(const float4*)(bp);
    float4 bv1 = *(const float4*)(bp + 4);
    float* op = &out[(size_t)c * HD + lane * 8];
    float4 o0 = make_float4(bv0.x + sc * acc[0], bv0.y + sc * acc[1],
                            bv0.z + sc * acc[2], bv0.w + sc * acc[3]);
    float4 o1 = make_float4(bv1.x + sc * acc[4], bv1.y + sc * acc[5],
                            bv1.z + sc * acc[6], bv1.w + sc * acc[7]);
    *(float4*)(op)     = o0;
    *(float4*)(op + 4) = o1;
}

extern "C" void kernel_launch(void* const* d_in, const int* in_sizes, int n_in,
                              void* d_out, int out_size, void* d_ws, size_t ws_size,
                              hipStream_t stream) {
    const float* x  = (const float*)d_in[0];
    const int*   ei = (const int*)d_in[1];   // [2][NE]: rows then cols
    const float* W  = (const float*)d_in[2];
    const float* b  = (const float*)d_in[3];
    float* out = (float*)d_out;

    ushort_t* g    = (ushort_t*)d_ws;                    // NN*HD bf16
    float* dinv    = (float*)(g + (size_t)NN * HD);      // NN
    int*   counts  = (int*)(dinv + NN);                  // NN
    int*   offsets = counts + NN;                        // NN+1
    int*   bsum    = offsets + NN + 1;                   // NBLK
    size_t wtoff   = (((size_t)((char*)(bsum + NBLK) - (char*)d_ws)) + 15) & ~(size_t)15;
    ushort_t* Wt   = (ushort_t*)((char*)d_ws + wtoff);   // HD*KF bf16 (16B aligned)
    ushort_t* srcs = Wt + (size_t)HD * KF;               // NE ushort
    ushort_t* aux  = srcs + NE;                          // NE ushort

    const int* rows = ei;
    const int* cols = ei + NE;

    hipMemsetAsync(counts, 0, NN * sizeof(int), stream);
    k_wt      <<<HD, 256, 0, stream>>>(W, Wt);
    k_slots   <<<(NE + 255) / 256, 256, 0, stream>>>(cols, counts, aux);
    k_blocksum<<<NBLK, 256, 0, stream>>>(counts, bsum);
    k_scanb   <<<1, 256, 0, stream>>>(bsum);
    k_offsets <<<NBLK, 256, 0, stream>>>(counts, bsum, offsets, dinv);
    k_fill    <<<(NE + 255) / 256, 256, 0, stream>>>(rows, cols, offsets, aux, srcs);
    k_gemm    <<<(NN + 63) / 64, 256, 0, stream>>>(x, Wt, dinv, g);
    k_aggregate<<<(int)(((size_t)NN * 16 + 255) / 256), 256, 0, stream>>>(
        offsets, srcs, g, dinv, b, out);
}